// Round 1
// baseline (438.655 us; speedup 1.0000x reference)
//
#include <hip/hip_runtime.h>
#include <math.h>

// Problem constants (FlaxHouseholderRoPE): B=2, S=4096, H=32, D=128, R=2
#define BB 2
#define SS 4096
#define HH 32
#define DD 128
#define EPS_C 1e-6f
// -log2(10000)/64  (inv_freq[p] = 10000^(-p/64) = exp2(p * C_LOG))
#define C_LOG (-0.20762050593046015f)

// Sum across each 32-lane half of the wave (masks < 32 never cross halves).
__device__ __forceinline__ float half_reduce(float v) {
    v += __shfl_xor(v, 1, 64);
    v += __shfl_xor(v, 2, 64);
    v += __shfl_xor(v, 4, 64);
    v += __shfl_xor(v, 8, 64);
    v += __shfl_xor(v, 16, 64);
    return v;
}

__global__ __launch_bounds__(256)
void hh_rope_kernel(const float* __restrict__ q, const float* __restrict__ k,
                    const float* __restrict__ pos, const float* __restrict__ refl,
                    float* __restrict__ oq, float* __restrict__ ok)
{
    const int lane   = threadIdx.x & 63;
    const int wid    = blockIdx.x * (blockDim.x >> 6) + (threadIdx.x >> 6);
    const int nW     = gridDim.x * (blockDim.x >> 6);
    const int hp     = wid & 15;        // h-pair index: wave covers h = 2*hp, 2*hp+1
    const int slice  = wid >> 4;
    const int nSlice = nW >> 4;
    const int half   = lane >> 5;       // which of the two rows this lane serves
    const int j      = lane & 31;       // float4 index within the 128-float row
    const int h      = hp * 2 + half;

    // Hoisted per-wave: reflector fragments + 2/(|v|^2 + eps)
    const float4 v0 = ((const float4*)(refl + (size_t)(h * 2 + 0) * DD))[j];
    const float4 v1 = ((const float4*)(refl + (size_t)(h * 2 + 1) * DD))[j];
    const float rs0 = 2.0f / (half_reduce(v0.x*v0.x + v0.y*v0.y + v0.z*v0.z + v0.w*v0.w) + EPS_C);
    const float rs1 = 2.0f / (half_reduce(v1.x*v1.x + v1.y*v1.y + v1.z*v1.z + v1.w*v1.w) + EPS_C);

    // Lane j holds RoPE pairs p0 = 2j (floats 4j,4j+1) and p1 = 2j+1 (floats 4j+2,4j+3)
    const float if0 = exp2f((float)(2 * j)     * C_LOG);
    const float if1 = exp2f((float)(2 * j + 1) * C_LOG);

    for (int bs = slice; bs < BB * SS; bs += nSlice) {
        const float p = pos[bs & (SS - 1)];           // s = bs % S
        const size_t off = ((size_t)bs * HH + h) * DD + 4 * (size_t)j;

        float4 xq = *(const float4*)(q + off);
        float4 xk = *(const float4*)(k + off);

        // ---- Householder reflector 0 ----
        float dq = half_reduce(xq.x*v0.x + xq.y*v0.y + xq.z*v0.z + xq.w*v0.w) * rs0;
        float dk = half_reduce(xk.x*v0.x + xk.y*v0.y + xk.z*v0.z + xk.w*v0.w) * rs0;
        xq.x -= dq * v0.x; xq.y -= dq * v0.y; xq.z -= dq * v0.z; xq.w -= dq * v0.w;
        xk.x -= dk * v0.x; xk.y -= dk * v0.y; xk.z -= dk * v0.z; xk.w -= dk * v0.w;

        // ---- Householder reflector 1 ----
        dq = half_reduce(xq.x*v1.x + xq.y*v1.y + xq.z*v1.z + xq.w*v1.w) * rs1;
        dk = half_reduce(xk.x*v1.x + xk.y*v1.y + xk.z*v1.z + xk.w*v1.w) * rs1;
        xq.x -= dq * v1.x; xq.y -= dq * v1.y; xq.z -= dq * v1.z; xq.w -= dq * v1.w;
        xk.x -= dk * v1.x; xk.y -= dk * v1.y; xk.z -= dk * v1.z; xk.w -= dk * v1.w;

        // ---- RoPE (interleaved pairs) ----
        float s0, c0, s1, c1;
        __sincosf(p * if0, &s0, &c0);
        __sincosf(p * if1, &s1, &c1);

        float4 rq, rk;
        rq.x = xq.x * c0 - xq.y * s0;  rq.y = xq.x * s0 + xq.y * c0;
        rq.z = xq.z * c1 - xq.w * s1;  rq.w = xq.z * s1 + xq.w * c1;
        rk.x = xk.x * c0 - xk.y * s0;  rk.y = xk.x * s0 + xk.y * c0;
        rk.z = xk.z * c1 - xk.w * s1;  rk.w = xk.z * s1 + xk.w * c1;

        *(float4*)(oq + off) = rq;
        *(float4*)(ok + off) = rk;
    }
}

extern "C" void kernel_launch(void* const* d_in, const int* in_sizes, int n_in,
                              void* d_out, int out_size, void* d_ws, size_t ws_size,
                              hipStream_t stream) {
    const float* q    = (const float*)d_in[0];
    const float* k    = (const float*)d_in[1];
    const float* pos  = (const float*)d_in[2];
    const float* refl = (const float*)d_in[3];

    float* oq = (float*)d_out;
    float* ok = oq + (size_t)BB * SS * HH * DD;   // outputs concatenated: (q_rope, k_rope)

    // 2048 blocks x 256 threads = 8192 waves = 16 h-pairs x 512 slices
    hh_rope_kernel<<<dim3(2048), dim3(256), 0, stream>>>(q, k, pos, refl, oq, ok);
}

// Round 3
// 426.683 us; speedup vs baseline: 1.0281x; 1.0281x over previous
//
#include <hip/hip_runtime.h>
#include <math.h>

// Problem constants (FlaxHouseholderRoPE): B=2, S=4096, H=32, D=128, R=2
#define BB 2
#define SS 4096
#define HH 32
#define DD 128
#define EPS_C 1e-6f
// -log2(10000)/64  (inv_freq[p] = 10000^(-p/64) = exp2(p * C_LOG))
#define C_LOG (-0.20762050593046015f)

// Native 16B vector type — required by __builtin_nontemporal_load/store
// (HIP's float4 is a class and is rejected by the builtin).
typedef float vf4 __attribute__((ext_vector_type(4)));

// Sum across each 32-lane half of the wave using single-instruction ds_swizzle
// (BitMode: offset = (xor<<10)|(or<<5)|and; and=0x1F confines to 32-lane groups).
__device__ __forceinline__ float hsum32(float v) {
    v += __int_as_float(__builtin_amdgcn_ds_swizzle(__float_as_int(v), 0x041F)); // xor 1
    v += __int_as_float(__builtin_amdgcn_ds_swizzle(__float_as_int(v), 0x081F)); // xor 2
    v += __int_as_float(__builtin_amdgcn_ds_swizzle(__float_as_int(v), 0x101F)); // xor 4
    v += __int_as_float(__builtin_amdgcn_ds_swizzle(__float_as_int(v), 0x201F)); // xor 8
    v += __int_as_float(__builtin_amdgcn_ds_swizzle(__float_as_int(v), 0x401F)); // xor 16
    return v;
}

__device__ __forceinline__ float dot4(vf4 a, vf4 b) {
    return a.x * b.x + a.y * b.y + a.z * b.z + a.w * b.w;
}

// Rank-2 composed Householder + RoPE epilogue for one vf4 fragment.
// c0 = rs0*d0 ; c1 = rs1*(d1 - c0*t01)  (equivalent to sequential reflections)
__device__ __forceinline__ vf4 finish(vf4 x, vf4 v0, vf4 v1,
                                      float d0, float d1,
                                      float rs0, float rs1, float t01,
                                      float sa, float ca, float sb, float cb) {
    const float c0 = d0 * rs0;
    const float c1 = (d1 - c0 * t01) * rs1;
    x.x -= c0 * v0.x + c1 * v1.x;
    x.y -= c0 * v0.y + c1 * v1.y;
    x.z -= c0 * v0.z + c1 * v1.z;
    x.w -= c0 * v0.w + c1 * v1.w;
    vf4 r;
    r.x = x.x * ca - x.y * sa;  r.y = x.x * sa + x.y * ca;
    r.z = x.z * cb - x.w * sb;  r.w = x.z * sb + x.w * cb;
    return r;
}

__global__ __launch_bounds__(256, 6)
void hh_rope_kernel(const float* __restrict__ q, const float* __restrict__ k,
                    const float* __restrict__ pos, const float* __restrict__ refl,
                    float* __restrict__ oq, float* __restrict__ ok)
{
    const int lane   = threadIdx.x & 63;
    const int wid    = (blockIdx.x << 2) + (threadIdx.x >> 6);
    const int hp     = wid & 15;        // wave covers heads h = 2*hp, 2*hp+1
    const int slice  = wid >> 4;        // 512 slices over bs
    const int half   = lane >> 5;
    const int j      = lane & 31;       // vf4 index within the 128-float row
    const int h      = (hp << 1) + half;

    // Hoisted per-wave: reflector fragments, 2/(|v|^2+eps), cross term v1.v0
    const vf4 v0 = ((const vf4*)(refl + (size_t)(h * 2 + 0) * DD))[j];
    const vf4 v1 = ((const vf4*)(refl + (size_t)(h * 2 + 1) * DD))[j];
    const float rs0 = 2.0f / (hsum32(dot4(v0, v0)) + EPS_C);
    const float rs1 = 2.0f / (hsum32(dot4(v1, v1)) + EPS_C);
    const float t01 = hsum32(dot4(v1, v0));

    // Lane j holds RoPE pairs 2j and 2j+1
    const float if0 = exp2f((float)(2 * j)     * C_LOG);
    const float if1 = exp2f((float)(2 * j + 1) * C_LOG);

    // 512 slices x (2 bs per unrolled iter) x 8 iters = 8192 bs values
    for (int bs = slice << 1; bs < BB * SS; bs += 1024) {
        const size_t row0 = ((size_t)bs * HH + h) * DD + 4 * (size_t)j;
        const size_t row1 = row0 + (size_t)HH * DD;

        // 4 KB of loads in flight before any dependent work
        vf4 xq0 = __builtin_nontemporal_load((const vf4*)(q + row0));
        vf4 xk0 = __builtin_nontemporal_load((const vf4*)(k + row0));
        vf4 xq1 = __builtin_nontemporal_load((const vf4*)(q + row1));
        vf4 xk1 = __builtin_nontemporal_load((const vf4*)(k + row1));

        const float p0 = pos[bs & (SS - 1)];
        const float p1 = pos[(bs + 1) & (SS - 1)];

        // sincos shared between q and k for each row; independent of the loads
        float sA0, cA0, sB0, cB0, sA1, cA1, sB1, cB1;
        __sincosf(p0 * if0, &sA0, &cA0);
        __sincosf(p0 * if1, &sB0, &cB0);
        __sincosf(p1 * if0, &sA1, &cA1);
        __sincosf(p1 * if1, &sB1, &cB1);

        // 8 fully independent reductions -> ds_swizzle chains pipeline
        const float dq00 = hsum32(dot4(xq0, v0));
        const float dq01 = hsum32(dot4(xq0, v1));
        const float dk00 = hsum32(dot4(xk0, v0));
        const float dk01 = hsum32(dot4(xk0, v1));
        const float dq10 = hsum32(dot4(xq1, v0));
        const float dq11 = hsum32(dot4(xq1, v1));
        const float dk10 = hsum32(dot4(xk1, v0));
        const float dk11 = hsum32(dot4(xk1, v1));

        vf4 r;
        r = finish(xq0, v0, v1, dq00, dq01, rs0, rs1, t01, sA0, cA0, sB0, cB0);
        __builtin_nontemporal_store(r, (vf4*)(oq + row0));
        r = finish(xk0, v0, v1, dk00, dk01, rs0, rs1, t01, sA0, cA0, sB0, cB0);
        __builtin_nontemporal_store(r, (vf4*)(ok + row0));
        r = finish(xq1, v0, v1, dq10, dq11, rs0, rs1, t01, sA1, cA1, sB1, cB1);
        __builtin_nontemporal_store(r, (vf4*)(oq + row1));
        r = finish(xk1, v0, v1, dk10, dk11, rs0, rs1, t01, sA1, cA1, sB1, cB1);
        __builtin_nontemporal_store(r, (vf4*)(ok + row1));
    }
}

extern "C" void kernel_launch(void* const* d_in, const int* in_sizes, int n_in,
                              void* d_out, int out_size, void* d_ws, size_t ws_size,
                              hipStream_t stream) {
    const float* q    = (const float*)d_in[0];
    const float* k    = (const float*)d_in[1];
    const float* pos  = (const float*)d_in[2];
    const float* refl = (const float*)d_in[3];

    float* oq = (float*)d_out;
    float* ok = oq + (size_t)BB * SS * HH * DD;   // outputs concatenated (q_rope, k_rope)

    // 2048 blocks x 256 threads = 8192 waves = 16 h-pairs x 512 slices
    hh_rope_kernel<<<dim3(2048), dim3(256), 0, stream>>>(q, k, pos, refl, oq, ok);
}